// Round 6
// baseline (157.117 us; speedup 1.0000x reference)
//
#include <hip/hip_runtime.h>
#include <hip/hip_bf16.h>
#include <cstdio>

typedef float f32x4 __attribute__((ext_vector_type(4)));
typedef __bf16 bf16x8 __attribute__((ext_vector_type(8)));

static constexpr int Bn = 8, Nn = 2048, Dn = 512, Hn = 512;

__device__ __forceinline__ unsigned short f2bf(float x) {
    union { float f; unsigned int u; } v; v.f = x;
    unsigned int r = (v.u + 0x7FFFu + ((v.u >> 16) & 1u)) >> 16;
    return (unsigned short)r;
}
__device__ __forceinline__ float bf2f(unsigned short h) {
    union { unsigned int u; float f; } v; v.u = ((unsigned int)h) << 16;
    return v.f;
}

__device__ __forceinline__ void gload_lds16(const unsigned short* g, unsigned short* l) {
    __builtin_amdgcn_global_load_lds(
        (const __attribute__((address_space(1))) void*)g,
        (__attribute__((address_space(3))) void*)l,
        16, 0, 0);
}

__device__ __forceinline__ int xcd_swizzle(int lin, int nwg) {
    return (lin & 7) * (nwg >> 3) + (lin >> 3);   // all grids %8==0
}

// ---------------- cast x (f32 -> bf16), flat ----------------
__global__ void cast_x_kernel(const float* __restrict__ x, unsigned short* __restrict__ xb, int n) {
    int i = (blockIdx.x * blockDim.x + threadIdx.x) * 8;
    if (i >= n) return;
    float4 a = *(const float4*)(x + i);
    float4 b = *(const float4*)(x + i + 4);
    unsigned short tmp[8] = {f2bf(a.x), f2bf(a.y), f2bf(a.z), f2bf(a.w),
                             f2bf(b.x), f2bf(b.y), f2bf(b.z), f2bf(b.w)};
    *(uint4*)(xb + i) = *(const uint4*)tmp;
}

// ---- weight transpose+cast: z=0 -> Wq, z=1 -> Wk; f32 [D][H] -> bf16 [H][D] ----
__global__ __launch_bounds__(256) void transpose_cast_w(
    const float* __restrict__ Wq, const float* __restrict__ Wk,
    unsigned short* __restrict__ out)
{
    __shared__ float tile[64][65];
    const int z = blockIdx.z;
    const float* inb = z ? Wk : Wq;
    unsigned short* outb = out + (size_t)z * Hn * Dn;
    const int r0 = blockIdx.y * 64, c0 = blockIdx.x * 64;
    const int tx = threadIdx.x & 63, ty = threadIdx.x >> 6;
#pragma unroll
    for (int p = 0; p < 64; p += 4) {
        const int r = p + ty;
        tile[r][tx] = inb[(size_t)(r0 + r) * Hn + c0 + tx];
    }
    __syncthreads();
#pragma unroll
    for (int p = 0; p < 64; p += 4) {
        const int oc = p + ty;
        outb[(size_t)(c0 + oc) * Dn + r0 + tx] = f2bf(tile[tx][oc]);
    }
}

// ---- xsT[b][d][j] = bf16(x_bf16[b][j][d] / s[b][j])  (bf16 source, 4x less traffic) ----
__global__ __launch_bounds__(256) void transpose_scale_bf16(
    const unsigned short* __restrict__ xb, unsigned short* __restrict__ out,
    const float* __restrict__ s)
{
    __shared__ unsigned short tile[64][65];
    const int z = blockIdx.z;
    const unsigned short* inb = xb + (size_t)z * Nn * Dn;
    unsigned short* ob = out + (size_t)z * Nn * Dn;
    const int j0 = blockIdx.y * 64, d0 = blockIdx.x * 64;
    const int tx = threadIdx.x & 63, ty = threadIdx.x >> 6;
#pragma unroll
    for (int p = 0; p < 64; p += 4) {
        const int r = p + ty;
        tile[r][tx] = inb[(size_t)(j0 + r) * Dn + d0 + tx];
    }
    __syncthreads();
    const float sv = s[(size_t)z * Nn + j0 + tx];
#pragma unroll
    for (int p = 0; p < 64; p += 4) {
        const int oc = p + ty;
        ob[(size_t)(d0 + oc) * Nn + j0 + tx] = f2bf(bf2f(tile[tx][oc]) / sv);
    }
}

// ---------------- combine per-block partial column sums ----------------
__global__ void combine_s_kernel(const float* __restrict__ s_part, float* __restrict__ s,
                                 int nblk, int total) {
    int i = blockIdx.x * blockDim.x + threadIdx.x;
    if (i >= total) return;
    int z = i >> 11, j = i & (Nn - 1);
    float acc = 0.f;
    for (int p = 0; p < nblk; ++p) acc += s_part[((size_t)z * nblk + p) * Nn + j];
    s[i] = acc;
}

// ============ 128x256 tile GEMM (C = A * B^T), BK=32, 4 waves, reg-pipelined ============
// Per-wave output 64x128 (acc 128 VGPR): 64 MFMA vs 12 ds_read_b128 per body ->
// MFMA-bound. 48 KB LDS dbuf + ~250 VGPR -> 2 blocks/CU (anti-phased blocks hide
// barrier/drain). Body T: lgkm0 (frag reads of buf[T] drained -> overwrite-safe);
// vmcnt(0) (own stage(T+1) done); barrier (=> ALL waves' stage(T+1) done -> LDS
// certified collectively); stage(T+2)->buf[T&1]; 32 MFMA on prefetched frags;
// ds_read frags(T+1) (overlaps 2nd MFMA half); 32 MFMA. Stage issued one full
// body (~1.2k cyc) before its drain -> latency hidden without counted vmcnt.
// LDS swizzle: 16B chunk c of row r stored at c^(r&3); stage source pre-permuted
// with the same involution; frag reads land 2-way bank-aliased (free).
// MODE 0: C bf16 [M][N] + bias split | MODE 1: C bf16=exp(acc) + col-sum partials
// MODE 2: C f32
template<int MODE>
__global__ __launch_bounds__(256, 2) void gemw(
    const unsigned short* __restrict__ A, long long sA, int lda,
    const unsigned short* __restrict__ Bt, long long sB, int ldb,
    void* __restrict__ Cp, long long sC,
    const float* __restrict__ bias, const float* __restrict__ bias2, int bsplit,
    float* __restrict__ s_part,
    int M, int N, int K, int gx, int gy)
{
    __shared__ unsigned short As[2][128 * 32];   // 8 KB per buf
    __shared__ unsigned short Bs[2][256 * 32];   // 16 KB per buf

    const int lin = xcd_swizzle(blockIdx.x, gridDim.x);
    const int bz = lin / (gx * gy);
    const int rem = lin - bz * gx * gy;
    const int by = rem / gx;
    const int bx = rem - by * gx;

    const unsigned short* Ab = A + (size_t)bz * sA;
    const unsigned short* Bb = Bt + (size_t)bz * sB;
    const int i0 = by * 128, j0 = bx * 256;

    const int t = threadIdx.x;
    const int lane = t & 63;
    const int w = t >> 6;              // wave 0..3
    const int wm = w >> 1, wn = w & 1; // per-wave C = 64 x 128
    const int l15 = lane & 15, g = lane >> 4;

    // stage lane geometry: per instr, 64 lanes = 16 rows x 4 chunks (16B)
    const int srow = lane >> 2;                  // 0..15
    const int sch = (lane & 3) ^ (srow & 3);     // pre-swizzled source chunk
    // frag read swizzled chunk byte offset (row&3 == l15&3)
    const int rdsw = (g ^ (l15 & 3)) * 16;

    f32x4 acc[4][8];
    const f32x4 zero4 = {0.f, 0.f, 0.f, 0.f};
#pragma unroll
    for (int mf = 0; mf < 4; ++mf)
#pragma unroll
        for (int nf = 0; nf < 8; ++nf) acc[mf][nf] = zero4;

    const int NT = K >> 5;   // BK=32; NT even (16 or 64 here)

#define STAGE_A(buf, Tn)                                                              \
    {                                                                                 \
        _Pragma("unroll") for (int i = 0; i < 2; ++i) {                               \
            const int row = i * 64 + w * 16 + srow;                                   \
            gload_lds16(Ab + (size_t)(i0 + row) * lda + (Tn) * 32 + sch * 8,          \
                        &As[buf][(i * 64 + w * 16) * 32]);                            \
        }                                                                             \
    }
#define STAGE_B(buf, Tn)                                                              \
    {                                                                                 \
        _Pragma("unroll") for (int i = 0; i < 4; ++i) {                               \
            const int row = i * 64 + w * 16 + srow;                                   \
            gload_lds16(Bb + (size_t)(j0 + row) * ldb + (Tn) * 32 + sch * 8,          \
                        &Bs[buf][(i * 64 + w * 16) * 32]);                            \
        }                                                                             \
    }
#define READS(fa, fb, buf)                                                            \
    {                                                                                 \
        _Pragma("unroll") for (int mf = 0; mf < 4; ++mf)                              \
            fa[mf] = *(const bf16x8*)((const char*)&As[buf][0]                        \
                        + (wm * 64 + mf * 16 + l15) * 64 + rdsw);                     \
        _Pragma("unroll") for (int nf = 0; nf < 8; ++nf)                              \
            fb[nf] = *(const bf16x8*)((const char*)&Bs[buf][0]                        \
                        + (wn * 128 + nf * 16 + l15) * 64 + rdsw);                    \
    }
#define MM(fa, fb, lo)                                                                \
    {                                                                                 \
        _Pragma("unroll") for (int mf = 0; mf < 4; ++mf)                              \
            _Pragma("unroll") for (int nf = (lo); nf < (lo) + 4; ++nf)                \
                acc[mf][nf] = __builtin_amdgcn_mfma_f32_16x16x32_bf16(                \
                    fa[mf], fb[nf], acc[mf][nf], 0, 0, 0);                            \
    }
#define BODY(fam, fbm, far, fbr, sbuf, rbuf, Tn)                                      \
    {                                                                                 \
        asm volatile("s_waitcnt lgkmcnt(0)" ::: "memory");                            \
        asm volatile("s_waitcnt vmcnt(0)" ::: "memory");                              \
        __builtin_amdgcn_s_barrier();                                                 \
        if ((Tn) + 2 < NT) { STAGE_A(sbuf, (Tn) + 2); STAGE_B(sbuf, (Tn) + 2); }      \
        MM(fam, fbm, 0);                                                              \
        if ((Tn) + 1 < NT) READS(far, fbr, rbuf);                                     \
        MM(fam, fbm, 4);                                                              \
    }

    bf16x8 a0[4], b0[8], a1[4], b1[8];

    // prologue: tiles 0,1 staged; certify tile 0 (leave tile 1's 6 loads in flight)
    STAGE_A(0, 0); STAGE_B(0, 0);
    STAGE_A(1, 1); STAGE_B(1, 1);
    asm volatile("s_waitcnt vmcnt(6)" ::: "memory");
    __builtin_amdgcn_s_barrier();
    READS(a0, b0, 0);

    const int NI = NT >> 1;
    for (int I = 0; I < NI; ++I) {
        const int t0 = 2 * I, t1 = 2 * I + 1;
        BODY(a0, b0, a1, b1, 0, 1, t0);   // MFMA P0; stage(t0+2)->buf0; read(t0+1)<-buf1
        BODY(a1, b1, a0, b0, 1, 0, t1);   // MFMA P1; stage(t1+2)->buf1; read(t1+1)<-buf0
    }
#undef BODY
#undef MM
#undef READS
#undef STAGE_A
#undef STAGE_B

    if (MODE == 0) {
        unsigned short* C = (unsigned short*)Cp;
        float bv[8];
#pragma unroll
        for (int nf = 0; nf < 8; ++nf) {
            const int col = j0 + wn * 128 + nf * 16 + l15;
            bv[nf] = (col < bsplit) ? bias[col] : bias2[col - bsplit];
        }
        const int col0 = j0 + wn * 128 + l15;
#pragma unroll
        for (int mf = 0; mf < 4; ++mf) {
            const int rb = i0 + wm * 64 + mf * 16 + g * 4;
#pragma unroll
            for (int r = 0; r < 4; ++r) {
                unsigned short* Crow = C + (size_t)(rb + r) * N + col0;
#pragma unroll
                for (int nf = 0; nf < 8; ++nf)
                    Crow[nf * 16] = f2bf(acc[mf][nf][r] + bv[nf]);
            }
        }
    } else if (MODE == 1) {
        unsigned short* C = (unsigned short*)Cp + (size_t)bz * sC;
        float cs[8] = {0.f, 0.f, 0.f, 0.f, 0.f, 0.f, 0.f, 0.f};
        const int col0 = j0 + wn * 128 + l15;
#pragma unroll
        for (int mf = 0; mf < 4; ++mf) {
            const int rb = i0 + wm * 64 + mf * 16 + g * 4;
#pragma unroll
            for (int r = 0; r < 4; ++r) {
                unsigned short* Crow = C + (size_t)(rb + r) * N + col0;
#pragma unroll
                for (int nf = 0; nf < 8; ++nf) {
                    const float e = __expf(acc[mf][nf][r]);
                    const unsigned short h = f2bf(e);
                    Crow[nf * 16] = h;
                    cs[nf] += bf2f(h);   // sum rounded value: num/denom consistency
                }
            }
        }
#pragma unroll
        for (int nf = 0; nf < 8; ++nf) {
            cs[nf] += __shfl_xor(cs[nf], 16);
            cs[nf] += __shfl_xor(cs[nf], 32);
        }
        __syncthreads();
        float* red = (float*)&As[0][0];   // [2][256] f32 = 2 KB
        if (g == 0) {
#pragma unroll
            for (int nf = 0; nf < 8; ++nf)
                red[wm * 256 + wn * 128 + nf * 16 + l15] = cs[nf];
        }
        __syncthreads();
        if (t < 256)
            s_part[((size_t)bz * gy + by) * Nn + j0 + t] = red[t] + red[256 + t];
    } else {
        float* C = (float*)Cp + (size_t)bz * sC;
        const int col0 = j0 + wn * 128 + l15;
#pragma unroll
        for (int mf = 0; mf < 4; ++mf) {
            const int rb = i0 + wm * 64 + mf * 16 + g * 4;
#pragma unroll
            for (int r = 0; r < 4; ++r) {
                float* Crow = C + (size_t)(rb + r) * N + col0;
#pragma unroll
                for (int nf = 0; nf < 8; ++nf)
                    Crow[nf * 16] = acc[mf][nf][r];
            }
        }
    }
}

extern "C" void kernel_launch(void* const* d_in, const int* in_sizes, int n_in,
                              void* d_out, int out_size, void* d_ws, size_t ws_size,
                              hipStream_t stream) {
    const float* x  = (const float*)d_in[0];
    const float* Wq = (const float*)d_in[1];
    const float* bq = (const float*)d_in[2];
    const float* Wk = (const float*)d_in[3];
    const float* bk = (const float*)d_in[4];
    float* out = (float*)d_out;

    char* ws = (char*)d_ws;
    unsigned short* xb    = (unsigned short*)(ws);                               // 16 MB
    unsigned short* qk    = (unsigned short*)(ws + (16ull << 20));               // 32 MB [16384][1024]
    unsigned short* WqkT  = (unsigned short*)(ws + (48ull << 20));               // 1 MB [1024][512]
    unsigned short* xsT   = (unsigned short*)(ws + (49ull << 20));               // 16 MB
    float*          s_prt = (float*)(ws + (65ull << 20));                        // 1 MB
    float*          s     = (float*)(ws + (66ull << 20));                        // 64 KB
    unsigned short* expE  = (unsigned short*)(ws + (67ull << 20));               // 64 MB
    if (ws_size < (131ull << 20)) {
        fprintf(stderr, "WS TOO SMALL: have %zu need %llu\n", ws_size, (131ull << 20));
    }

    // 1) xb = bf16(x)
    cast_x_kernel<<<dim3((Bn * Nn * Dn) / (8 * 256)), 256, 0, stream>>>(x, xb, Bn * Nn * Dn);
    // 2) WqkT = bf16([Wq; Wk]^T)  (one dispatch, z = which weight)
    transpose_cast_w<<<dim3(Hn / 64, Dn / 64, 2), 256, 0, stream>>>(Wq, Wk, WqkT);
    // 3) qk = xb @ [Wq|Wk] + [bq|bk]   (M=16384, N=1024, K=512) — 4 x 128 = 512 blocks
    {
        const int gx = (2 * Hn) / 256, gy = (Bn * Nn) / 128;
        gemw<0><<<dim3(gx * gy), 256, 0, stream>>>(
            xb, 0, Dn, WqkT, 0, Dn, qk, 0, bq, bk, Hn, nullptr,
            Bn * Nn, 2 * Hn, Dn, gx, gy);
    }
    // 4) expE = exp(q @ k^T) + col-sum partials (per batch; M=N=2048, K=512) — 8x16x8 = 1024 blocks
    {
        const int gx = Nn / 256, gy = Nn / 128;
        gemw<1><<<dim3(gx * gy * Bn), 256, 0, stream>>>(
            qk, (long long)Nn * 2 * Hn, 2 * Hn,               // q = qk[:, 0:512]
            qk + Hn, (long long)Nn * 2 * Hn, 2 * Hn,          // k = qk[:, 512:1024]
            expE, (long long)Nn * Nn, nullptr, nullptr, 0, s_prt,
            Nn, Nn, Hn, gx, gy);
    }
    // 5) s[b][j] = sum of partials (16 m-blocks per batch)
    combine_s_kernel<<<dim3((Bn * Nn) / 256), 256, 0, stream>>>(s_prt, s, Nn / 128, Bn * Nn);
    // 6) xsT[b][d][j] = bf16(xb[b][j][d] / s[b][j])  (bf16 source)
    transpose_scale_bf16<<<dim3(Dn / 64, Nn / 64, Bn), 256, 0, stream>>>(xb, xsT, s);
    // 7) out = expE @ xsT^T   (per batch; M=2048, N=512, K=2048) — 2 x 16 x 8 = 256 blocks
    {
        const int gx = Dn / 256, gy = Nn / 128;
        gemw<2><<<dim3(gx * gy * Bn), 256, 0, stream>>>(
            expE, (long long)Nn * Nn, Nn, xsT, (long long)Dn * Nn, Nn,
            out, (long long)Nn * Dn, nullptr, nullptr, 0, nullptr,
            Nn, Dn, Nn, gx, gy);
    }
}